// Round 3
// baseline (256.566 us; speedup 1.0000x reference)
//
#include <hip/hip_runtime.h>
#include <hip/hip_bf16.h>

typedef unsigned short u16;
typedef short bf16x8 __attribute__((ext_vector_type(8)));
typedef float f32x4 __attribute__((ext_vector_type(4)));

#define NROWS 8192
#define EMBD  1140
#define FDIM  3968   // 32*124
#define N1R   1000
#define N1P   1024
#define N2R   100
#define N2P   128
#define DG    512

__device__ inline u16 f2b(float f) {
  __hip_bfloat16 h = __float2bfloat16(f);
  return *reinterpret_cast<u16*>(&h);
}

__device__ inline float tanh_fast(float x) {
  float ax = fabsf(x);
  float t = __expf(-2.f * ax);
  float r = (1.f - t) / (1.f + t);
  return x < 0.f ? -r : r;
}

// async global->LDS, 16B per lane; LDS dest = wave-uniform base + lane*16
__device__ inline void gld16(const void* g, void* l) {
  __builtin_amdgcn_global_load_lds(
      (const __attribute__((address_space(1))) unsigned int*)g,
      (__attribute__((address_space(3))) unsigned int*)l, 16, 0, 0);
}

// ---------------- conversion: pad-to-[NP][KP] f32 -> bf16 ----------------
__global__ void cvt_pad2_kernel(const float* __restrict__ in, u16* __restrict__ out,
                                int realN, int realK, int NP, int KP) {
  long total = (long)NP * KP;
  long stride = (long)gridDim.x * blockDim.x;
  for (long i = (long)blockIdx.x * blockDim.x + threadIdx.x; i < total; i += stride) {
    int n = (int)(i / KP);
    int k = (int)(i - (long)n * KP);
    float v = (n < realN && k < realK) ? in[(long)n * realK + k] : 0.f;
    out[i] = f2b(v);
  }
}

// ---------------- separable conv precompute ----------------
__global__ __launch_bounds__(256) void precomp_ab_kernel(
    const float* __restrict__ H_emb, const float* __restrict__ conv_w,
    const float* __restrict__ conv_b, float* __restrict__ Abuf, float* __restrict__ Bbuf) {
  int b = blockIdx.x;
  bool isA = b < 240;
  const float* emb = H_emb + (size_t)b * EMBD;
  float* outp = isA ? (Abuf + (size_t)b * FDIM) : (Bbuf + (size_t)(b - 240) * FDIM);
  __shared__ float se[EMBD];
  __shared__ float sw[32 * 25];
  __shared__ float sb[32];
  int t = threadIdx.x;
  for (int i = t; i < EMBD; i += 256) se[i] = emb[i];
  int kh = isA ? 0 : 1;
  for (int i = t; i < 800; i += 256) {
    int o = i / 25, kw = i - o * 25;
    sw[i] = conv_w[o * 50 + kh * 25 + kw];
  }
  if (t < 32) sb[t] = isA ? conv_b[t] : 0.f;
  __syncthreads();
  for (int f = t; f < FDIM; f += 256) {
    int o = f / 124, wpos = f - o * 124;
    const float* e = se + wpos * 9;
    const float* wp = sw + o * 25;
    float acc = sb[o];
#pragma unroll
    for (int kw = 0; kw < 25; ++kw) acc += wp[kw] * e[kw];
    outp[f] = acc;
  }
}

// c[r][f] = lrelu(A[x[r]][f] + B[y[r]][f])  -> bf16
__global__ __launch_bounds__(256) void conv_combine_kernel(
    const float* __restrict__ Abuf, const float* __restrict__ Bbuf,
    const int* __restrict__ xi, const int* __restrict__ yi, u16* __restrict__ cbf) {
  int r = blockIdx.x;
  const float4* pa = (const float4*)(Abuf + (size_t)xi[r] * FDIM);
  const float4* pb = (const float4*)(Bbuf + (size_t)yi[r] * FDIM);
  u16* out = cbf + (size_t)r * FDIM;
  for (int i = threadIdx.x; i < FDIM / 4; i += 256) {
    float4 a = pa[i], b = pb[i];
    float v0 = a.x + b.x, v1 = a.y + b.y, v2 = a.z + b.z, v3 = a.w + b.w;
    v0 = v0 > 0.f ? v0 : 0.01f * v0;
    v1 = v1 > 0.f ? v1 : 0.01f * v1;
    v2 = v2 > 0.f ? v2 : 0.01f * v2;
    v3 = v3 > 0.f ? v3 : 0.01f * v3;
    ushort4 o;
    o.x = f2b(v0); o.y = f2b(v1); o.z = f2b(v2); o.w = f2b(v3);
    *(ushort4*)(out + i * 4) = o;
  }
}

// ---------------- FC1: bf16 MFMA GEMM, global_load_lds staging (m97 structure) ----------------
__global__ __launch_bounds__(256) void fc1_kernel(
    const u16* __restrict__ A, const u16* __restrict__ B,
    const float* __restrict__ bias, int realN,
    u16* __restrict__ C, int K, int ldc, int nTilesX) {
  const int nwg = gridDim.x;
  const int cpx = nwg >> 3;
  const int bid = blockIdx.x;
  const int wg = (bid & 7) * cpx + (bid >> 3);   // XCD gets contiguous wg chunk
  const int tm = (wg / nTilesX) * 128;
  const int tn = (wg % nTilesX) * 128;

  __shared__ u16 As[128 * 32];
  __shared__ u16 Bs[128 * 32];
  const int t = threadIdx.x;
  const int lane = t & 63;
  const int w = t >> 6;
  const int wr = (w >> 1) * 64, wc = (w & 1) * 64;
  const int fr = lane & 15;
  const int kg = lane >> 4;

  const int grow = w * 16 + (lane >> 2);
  const int gcol = (lane & 3) * 8;
  const u16* gA0 = A + (size_t)(tm + grow) * K + gcol;
  const u16* gA1 = A + (size_t)(tm + grow + 64) * K + gcol;
  const u16* gB0 = B + (size_t)(tn + grow) * K + gcol;
  const u16* gB1 = B + (size_t)(tn + grow + 64) * K + gcol;
  u16* lA0 = As + w * 512;
  u16* lA1 = lA0 + 4 * 512;
  u16* lB0 = Bs + w * 512;
  u16* lB1 = lB0 + 4 * 512;

  f32x4 acc[4][4];
#pragma unroll
  for (int m = 0; m < 4; ++m)
#pragma unroll
    for (int n = 0; n < 4; ++n) acc[m][n] = (f32x4){0.f, 0.f, 0.f, 0.f};

  const int nk = K >> 5;
  for (int kt = 0; kt < nk; ++kt) {
    __syncthreads();
    const int ko = kt * 32;
    gld16(gA0 + ko, lA0);
    gld16(gA1 + ko, lA1);
    gld16(gB0 + ko, lB0);
    gld16(gB1 + ko, lB1);
    __syncthreads();   // drains vmcnt before compute
    bf16x8 af[4], bff[4];
#pragma unroll
    for (int m = 0; m < 4; ++m)
      af[m] = *(const bf16x8*)(As + (wr + m * 16 + fr) * 32 + kg * 8);
#pragma unroll
    for (int n = 0; n < 4; ++n)
      bff[n] = *(const bf16x8*)(Bs + (wc + n * 16 + fr) * 32 + kg * 8);
#pragma unroll
    for (int m = 0; m < 4; ++m)
#pragma unroll
      for (int n = 0; n < 4; ++n)
        acc[m][n] = __builtin_amdgcn_mfma_f32_16x16x32_bf16(af[m], bff[n], acc[m][n], 0, 0, 0);
  }

  // epilogue: C/D layout col=lane&15, row=(lane>>4)*4+j  [m89/m91]
#pragma unroll
  for (int n = 0; n < 4; ++n) {
    int col = tn + wc + n * 16 + fr;
    float bv = (col < realN) ? bias[col] : 0.f;
#pragma unroll
    for (int m = 0; m < 4; ++m) {
#pragma unroll
      for (int j = 0; j < 4; ++j) {
        int row = tm + wr + m * 16 + kg * 4 + j;
        float v = acc[m][n][j] + bv;
        v = v > 0.f ? v : 0.01f * v;
        C[(size_t)row * ldc + col] = f2b(v);
      }
    }
  }
}

// ---------------- fused tail: FC2 + gate GEMMs + dots + softmax + scale ----------------
__global__ __launch_bounds__(256) void tail_kernel(
    const u16* __restrict__ hfc1, const u16* __restrict__ W2bf, const float* __restrict__ b2,
    const float* __restrict__ ldg, const float* __restrict__ lde,
    const u16* __restrict__ Wgbf, const float* __restrict__ bg,
    const u16* __restrict__ Webf, const float* __restrict__ be,
    float* __restrict__ out0, float* __restrict__ out1) {
  __shared__ u16 As[128 * 32];
  __shared__ u16 Bs[128 * 32];
  __shared__ float sdg[256];   // [row][half]
  __shared__ float sde[256];
  __shared__ float swt[256];   // [row][2] softmax weights

  const int tm = blockIdx.x * 128;
  const int t = threadIdx.x;
  const int lane = t & 63;
  const int w = t >> 6;
  const int wr = (w >> 1) * 64, wc = (w & 1) * 64;
  const int fr = lane & 15;
  const int kg = lane >> 4;

  const int grow = w * 16 + (lane >> 2);
  const int gcol = (lane & 3) * 8;
  u16* lA0 = As + w * 512;
  u16* lA1 = lA0 + 4 * 512;
  u16* lB0 = Bs + w * 512;
  u16* lB1 = lB0 + 4 * 512;

  f32x4 acc[4][4], hreg[4][4];

#define ZERO_ACC() \
  _Pragma("unroll") for (int m = 0; m < 4; ++m) \
  _Pragma("unroll") for (int n = 0; n < 4; ++n) acc[m][n] = (f32x4){0.f, 0.f, 0.f, 0.f}

#define MFMA_STEP() do { \
    bf16x8 af[4], bff[4]; \
    _Pragma("unroll") for (int m = 0; m < 4; ++m) \
      af[m] = *(const bf16x8*)(As + (wr + m * 16 + fr) * 32 + kg * 8); \
    _Pragma("unroll") for (int n = 0; n < 4; ++n) \
      bff[n] = *(const bf16x8*)(Bs + (wc + n * 16 + fr) * 32 + kg * 8); \
    _Pragma("unroll") for (int m = 0; m < 4; ++m) \
    _Pragma("unroll") for (int n = 0; n < 4; ++n) \
      acc[m][n] = __builtin_amdgcn_mfma_f32_16x16x32_bf16(af[m], bff[n], acc[m][n], 0, 0, 0); \
  } while (0)

  // ---- Section H: hfc2 = lrelu(hfc1 @ W2^T + b2), K=1024, kept in registers ----
  {
    ZERO_ACC();
    const u16* gA0 = hfc1 + (size_t)(tm + grow) * N1P + gcol;
    const u16* gA1 = gA0 + (size_t)64 * N1P;
    const u16* gB0 = W2bf + (size_t)grow * N1P + gcol;
    const u16* gB1 = gB0 + (size_t)64 * N1P;
    for (int kt = 0; kt < N1P / 32; ++kt) {
      __syncthreads();
      const int ko = kt * 32;
      gld16(gA0 + ko, lA0);
      gld16(gA1 + ko, lA1);
      gld16(gB0 + ko, lB0);
      gld16(gB1 + ko, lB1);
      __syncthreads();
      MFMA_STEP();
    }
#pragma unroll
    for (int n = 0; n < 4; ++n) {
      int col = wc + n * 16 + fr;
      float bv = (col < N2R) ? b2[col] : 0.f;
#pragma unroll
      for (int m = 0; m < 4; ++m)
#pragma unroll
        for (int j = 0; j < 4; ++j) {
          float v = acc[m][n][j] + bv;
          hreg[m][n][j] = v > 0.f ? v : 0.01f * v;
        }
    }
  }

  // ---- Sections G/E: gate = tanh(ld @ W^T + b); dot with hreg; reduce ----
  // A reg-stage coverage: r0 = t>>2 (0..63), c8 = (t&3)*8 -> 8 u16 per row,
  // rows r0 and r0+64 => full 128x32 tile (fixes round-2 half-coverage bug).
  const int r0 = t >> 2;
  const int c8 = (t & 3) * 8;
#pragma unroll 1
  for (int sec = 0; sec < 2; ++sec) {
    const float* ld = sec == 0 ? ldg : lde;
    const u16* Wb = sec == 0 ? Wgbf : Webf;
    const float* bb = sec == 0 ? bg : be;
    float* sd = sec == 0 ? sdg : sde;

    ZERO_ACC();
    const u16* gB0 = Wb + (size_t)grow * DG + gcol;
    const u16* gB1 = gB0 + (size_t)64 * DG;
    for (int kt = 0; kt < DG / 32; ++kt) {
      __syncthreads();
      const int ko = kt * 32;
      {
        const float* p0 = ld + (size_t)(tm + r0) * DG + ko + c8;
        float4 v0 = *(const float4*)(p0);
        float4 v1 = *(const float4*)(p0 + 4);
        bf16x8 o;
        o[0] = (short)f2b(v0.x); o[1] = (short)f2b(v0.y);
        o[2] = (short)f2b(v0.z); o[3] = (short)f2b(v0.w);
        o[4] = (short)f2b(v1.x); o[5] = (short)f2b(v1.y);
        o[6] = (short)f2b(v1.z); o[7] = (short)f2b(v1.w);
        *(bf16x8*)(As + r0 * 32 + c8) = o;
        const float* p1 = ld + (size_t)(tm + r0 + 64) * DG + ko + c8;
        float4 v2 = *(const float4*)(p1);
        float4 v3 = *(const float4*)(p1 + 4);
        bf16x8 o2;
        o2[0] = (short)f2b(v2.x); o2[1] = (short)f2b(v2.y);
        o2[2] = (short)f2b(v2.z); o2[3] = (short)f2b(v2.w);
        o2[4] = (short)f2b(v3.x); o2[5] = (short)f2b(v3.y);
        o2[6] = (short)f2b(v3.z); o2[7] = (short)f2b(v3.w);
        *(bf16x8*)(As + (r0 + 64) * 32 + c8) = o2;
      }
      gld16(gB0 + ko, lB0);
      gld16(gB1 + ko, lB1);
      __syncthreads();
      MFMA_STEP();
    }
    // epilogue: tanh + elementwise dot with hreg, accumulate per-row
    float dv[4][4];
#pragma unroll
    for (int m = 0; m < 4; ++m)
#pragma unroll
      for (int j = 0; j < 4; ++j) dv[m][j] = 0.f;
#pragma unroll
    for (int n = 0; n < 4; ++n) {
      int col = wc + n * 16 + fr;
      float bv = (col < N2R) ? bb[col] : 0.f;
#pragma unroll
      for (int m = 0; m < 4; ++m)
#pragma unroll
        for (int j = 0; j < 4; ++j) {
          float gv = tanh_fast(acc[m][n][j] + bv);
          dv[m][j] += gv * hreg[m][n][j];
        }
    }
    // reduce over the 16-lane fr group (cols)
#pragma unroll
    for (int m = 0; m < 4; ++m)
#pragma unroll
      for (int j = 0; j < 4; ++j) {
        float v = dv[m][j];
        v += __shfl_xor(v, 1);
        v += __shfl_xor(v, 2);
        v += __shfl_xor(v, 4);
        v += __shfl_xor(v, 8);
        dv[m][j] = v;
      }
    if (fr == 0) {
#pragma unroll
      for (int m = 0; m < 4; ++m)
#pragma unroll
        for (int j = 0; j < 4; ++j) {
          int row = wr + m * 16 + kg * 4 + j;
          sd[row * 2 + (wc >> 6)] = dv[m][j];
        }
    }
  }
  __syncthreads();

  // ---- softmax per row ----
  if (t < 128) {
    float ag = sdg[t * 2] + sdg[t * 2 + 1];
    float ae = sde[t * 2] + sde[t * 2 + 1];
    float mm = fmaxf(ag, ae);
    float eg = __expf(ag - mm), eo = __expf(ae - mm);
    float inv = 1.f / (eg + eo);
    swt[t * 2] = eg * inv;
    swt[t * 2 + 1] = eo * inv;
  }
  __syncthreads();

  // ---- scale + write both outputs ----
  for (int i = t; i < 128 * 128; i += 256) {
    int r = i >> 7, c = i & 127;
    float w0 = swt[r * 2], w1 = swt[r * 2 + 1];
    size_t off = (size_t)(tm + r) * DG + c * 4;
    float4 a = *(const float4*)(ldg + off);
    a.x *= w0; a.y *= w0; a.z *= w0; a.w *= w0;
    *(float4*)(out0 + off) = a;
    float4 b = *(const float4*)(lde + off);
    b.x *= w1; b.y *= w1; b.z *= w1; b.w *= w1;
    *(float4*)(out1 + off) = b;
  }
#undef ZERO_ACC
#undef MFMA_STEP
}

extern "C" void kernel_launch(void* const* d_in, const int* in_sizes, int n_in,
                              void* d_out, int out_size, void* d_ws, size_t ws_size,
                              hipStream_t stream) {
  const float* ld_gcn = (const float*)d_in[0];
  const float* ld_enc = (const float*)d_in[1];
  const int*   xi     = (const int*)d_in[2];
  const int*   yi     = (const int*)d_in[3];
  const float* H_emb  = (const float*)d_in[4];
  const float* conv_w = (const float*)d_in[5];
  const float* conv_b = (const float*)d_in[6];
  const float* W1     = (const float*)d_in[7];
  const float* b1     = (const float*)d_in[8];
  const float* W2     = (const float*)d_in[9];
  const float* b2     = (const float*)d_in[10];
  const float* Wg     = (const float*)d_in[11];
  const float* bg     = (const float*)d_in[12];
  const float* We     = (const float*)d_in[13];
  const float* be     = (const float*)d_in[14];

  char* ws = (char*)d_ws;
  size_t off = 0;
  auto alloc = [&](size_t bytes) -> void* {
    void* p = ws + off;
    off = (off + bytes + 255) & ~(size_t)255;
    return p;
  };
  float* Abuf = (float*)alloc(240ull * FDIM * 4);
  float* Bbuf = (float*)alloc(404ull * FDIM * 4);
  u16*   cbf  = (u16*)  alloc((size_t)NROWS * FDIM * 2);
  u16*   W1bf = (u16*)  alloc((size_t)N1P * FDIM * 2);
  u16*   W2bf = (u16*)  alloc((size_t)N2P * N1P * 2);
  u16*   Wgbf = (u16*)  alloc((size_t)N2P * DG * 2);
  u16*   Webf = (u16*)  alloc((size_t)N2P * DG * 2);
  u16*   hfc1 = (u16*)  alloc((size_t)NROWS * N1P * 2);
  if (ws_size < off) return;  // ~101 MB needed

  cvt_pad2_kernel<<<4096, 256, 0, stream>>>(W1, W1bf, N1R, FDIM, N1P, FDIM);
  cvt_pad2_kernel<<<512, 256, 0, stream>>>(W2, W2bf, N2R, N1R, N2P, N1P);
  cvt_pad2_kernel<<<256, 256, 0, stream>>>(Wg, Wgbf, N2R, DG, N2P, DG);
  cvt_pad2_kernel<<<256, 256, 0, stream>>>(We, Webf, N2R, DG, N2P, DG);
  precomp_ab_kernel<<<644, 256, 0, stream>>>(H_emb, conv_w, conv_b, Abuf, Bbuf);
  conv_combine_kernel<<<NROWS, 256, 0, stream>>>(Abuf, Bbuf, xi, yi, cbf);

  fc1_kernel<<<dim3((NROWS / 128) * (N1P / 128)), 256, 0, stream>>>(
      cbf, W1bf, b1, N1R, hfc1, FDIM, N1P, N1P / 128);

  float* out0 = (float*)d_out;
  float* out1 = out0 + (size_t)NROWS * DG;
  tail_kernel<<<NROWS / 128, 256, 0, stream>>>(
      hfc1, W2bf, b2, ld_gcn, ld_enc, Wgbf, bg, Webf, be, out0, out1);
}

// Round 4
// 219.764 us; speedup vs baseline: 1.1675x; 1.1675x over previous
//
#include <hip/hip_runtime.h>
#include <hip/hip_bf16.h>

typedef unsigned short u16;
typedef short bf16x8 __attribute__((ext_vector_type(8)));
typedef float f32x4 __attribute__((ext_vector_type(4)));

#define NROWS 8192
#define EMBD  1140
#define FDIM  3968   // 32*124
#define N1R   1000
#define N1P   1024
#define N2R   100
#define N2P   128
#define DG    512

__device__ inline u16 f2b(float f) {
  __hip_bfloat16 h = __float2bfloat16(f);
  return *reinterpret_cast<u16*>(&h);
}

__device__ inline float tanh_fast(float x) {
  float ax = fabsf(x);
  float t = __expf(-2.f * ax);
  float r = (1.f - t) / (1.f + t);
  return x < 0.f ? -r : r;
}

// async global->LDS, 16B per lane; LDS dest = wave-uniform base + lane*16
__device__ inline void gld16(const void* g, void* l) {
  __builtin_amdgcn_global_load_lds(
      (const __attribute__((address_space(1))) unsigned int*)g,
      (__attribute__((address_space(3))) unsigned int*)l, 16, 0, 0);
}

// ---------------- conversion: pad-to-[NP][KP] f32 -> bf16 ----------------
__global__ void cvt_pad2_kernel(const float* __restrict__ in, u16* __restrict__ out,
                                int realN, int realK, int NP, int KP) {
  long total = (long)NP * KP;
  long stride = (long)gridDim.x * blockDim.x;
  for (long i = (long)blockIdx.x * blockDim.x + threadIdx.x; i < total; i += stride) {
    int n = (int)(i / KP);
    int k = (int)(i - (long)n * KP);
    float v = (n < realN && k < realK) ? in[(long)n * realK + k] : 0.f;
    out[i] = f2b(v);
  }
}

// ---------------- separable conv precompute ----------------
__global__ __launch_bounds__(256) void precomp_ab_kernel(
    const float* __restrict__ H_emb, const float* __restrict__ conv_w,
    const float* __restrict__ conv_b, float* __restrict__ Abuf, float* __restrict__ Bbuf) {
  int b = blockIdx.x;
  bool isA = b < 240;
  const float* emb = H_emb + (size_t)b * EMBD;
  float* outp = isA ? (Abuf + (size_t)b * FDIM) : (Bbuf + (size_t)(b - 240) * FDIM);
  __shared__ float se[EMBD];
  __shared__ float sw[32 * 25];
  __shared__ float sb[32];
  int t = threadIdx.x;
  for (int i = t; i < EMBD; i += 256) se[i] = emb[i];
  int kh = isA ? 0 : 1;
  for (int i = t; i < 800; i += 256) {
    int o = i / 25, kw = i - o * 25;
    sw[i] = conv_w[o * 50 + kh * 25 + kw];
  }
  if (t < 32) sb[t] = isA ? conv_b[t] : 0.f;
  __syncthreads();
  for (int f = t; f < FDIM; f += 256) {
    int o = f / 124, wpos = f - o * 124;
    const float* e = se + wpos * 9;
    const float* wp = sw + o * 25;
    float acc = sb[o];
#pragma unroll
    for (int kw = 0; kw < 25; ++kw) acc += wp[kw] * e[kw];
    outp[f] = acc;
  }
}

// c[r][f] = lrelu(A[x[r]][f] + B[y[r]][f])  -> bf16
__global__ __launch_bounds__(256) void conv_combine_kernel(
    const float* __restrict__ Abuf, const float* __restrict__ Bbuf,
    const int* __restrict__ xi, const int* __restrict__ yi, u16* __restrict__ cbf) {
  int r = blockIdx.x;
  const float4* pa = (const float4*)(Abuf + (size_t)xi[r] * FDIM);
  const float4* pb = (const float4*)(Bbuf + (size_t)yi[r] * FDIM);
  u16* out = cbf + (size_t)r * FDIM;
  for (int i = threadIdx.x; i < FDIM / 4; i += 256) {
    float4 a = pa[i], b = pb[i];
    float v0 = a.x + b.x, v1 = a.y + b.y, v2 = a.z + b.z, v3 = a.w + b.w;
    v0 = v0 > 0.f ? v0 : 0.01f * v0;
    v1 = v1 > 0.f ? v1 : 0.01f * v1;
    v2 = v2 > 0.f ? v2 : 0.01f * v2;
    v3 = v3 > 0.f ? v3 : 0.01f * v3;
    ushort4 o;
    o.x = f2b(v0); o.y = f2b(v1); o.z = f2b(v2); o.w = f2b(v3);
    *(ushort4*)(out + i * 4) = o;
  }
}

// ---------------- FC1: bf16 MFMA GEMM, global_load_lds staging (m97 structure) ----------------
__global__ __launch_bounds__(256) void fc1_kernel(
    const u16* __restrict__ A, const u16* __restrict__ B,
    const float* __restrict__ bias, int realN,
    u16* __restrict__ C, int K, int ldc, int nTilesX) {
  const int nwg = gridDim.x;
  const int cpx = nwg >> 3;
  const int bid = blockIdx.x;
  const int wg = (bid & 7) * cpx + (bid >> 3);   // XCD gets contiguous wg chunk
  const int tm = (wg / nTilesX) * 128;
  const int tn = (wg % nTilesX) * 128;

  __shared__ u16 As[128 * 32];
  __shared__ u16 Bs[128 * 32];
  const int t = threadIdx.x;
  const int lane = t & 63;
  const int w = t >> 6;
  const int wr = (w >> 1) * 64, wc = (w & 1) * 64;
  const int fr = lane & 15;
  const int kg = lane >> 4;

  const int grow = w * 16 + (lane >> 2);
  const int gcol = (lane & 3) * 8;
  const u16* gA0 = A + (size_t)(tm + grow) * K + gcol;
  const u16* gA1 = A + (size_t)(tm + grow + 64) * K + gcol;
  const u16* gB0 = B + (size_t)(tn + grow) * K + gcol;
  const u16* gB1 = B + (size_t)(tn + grow + 64) * K + gcol;
  u16* lA0 = As + w * 512;
  u16* lA1 = lA0 + 4 * 512;
  u16* lB0 = Bs + w * 512;
  u16* lB1 = lB0 + 4 * 512;

  f32x4 acc[4][4];
#pragma unroll
  for (int m = 0; m < 4; ++m)
#pragma unroll
    for (int n = 0; n < 4; ++n) acc[m][n] = (f32x4){0.f, 0.f, 0.f, 0.f};

  const int nk = K >> 5;
  for (int kt = 0; kt < nk; ++kt) {
    __syncthreads();
    const int ko = kt * 32;
    gld16(gA0 + ko, lA0);
    gld16(gA1 + ko, lA1);
    gld16(gB0 + ko, lB0);
    gld16(gB1 + ko, lB1);
    __syncthreads();   // drains vmcnt before compute
    bf16x8 af[4], bff[4];
#pragma unroll
    for (int m = 0; m < 4; ++m)
      af[m] = *(const bf16x8*)(As + (wr + m * 16 + fr) * 32 + kg * 8);
#pragma unroll
    for (int n = 0; n < 4; ++n)
      bff[n] = *(const bf16x8*)(Bs + (wc + n * 16 + fr) * 32 + kg * 8);
#pragma unroll
    for (int m = 0; m < 4; ++m)
#pragma unroll
      for (int n = 0; n < 4; ++n)
        acc[m][n] = __builtin_amdgcn_mfma_f32_16x16x32_bf16(af[m], bff[n], acc[m][n], 0, 0, 0);
  }

  // epilogue: C/D layout col=lane&15, row=(lane>>4)*4+j  [m89/m91]
#pragma unroll
  for (int n = 0; n < 4; ++n) {
    int col = tn + wc + n * 16 + fr;
    float bv = (col < realN) ? bias[col] : 0.f;
#pragma unroll
    for (int m = 0; m < 4; ++m) {
#pragma unroll
      for (int j = 0; j < 4; ++j) {
        int row = tm + wr + m * 16 + kg * 4 + j;
        float v = acc[m][n][j] + bv;
        v = v > 0.f ? v : 0.01f * v;
        C[(size_t)row * ldc + col] = f2b(v);
      }
    }
  }
}

// ---------------- fused tail v2: barrier-free GEMM sections, 512 blocks ----------------
// Block = 16 rows, 4 waves; wave w owns cols [w*32, w*32+32) with FULL-K serial
// accumulation, fragments read directly from global (A rows -> L1, weights -> L2).
// No LDS staging, no per-K barriers. hfc2 kept in LDS [col][row] f32.
__global__ __launch_bounds__(256) void tail_kernel(
    const u16* __restrict__ hfc1, const u16* __restrict__ W2bf, const float* __restrict__ b2,
    const float* __restrict__ ldg, const float* __restrict__ lde,
    const u16* __restrict__ Wgbf, const float* __restrict__ bg,
    const u16* __restrict__ Webf, const float* __restrict__ be,
    float* __restrict__ out0, float* __restrict__ out1) {
  __shared__ float H16[N2P][16];     // [col][row] hfc2 tile, f32x4-aligned rows
  __shared__ float dpart[2][4][16];  // [sec][wave][row] partial dots
  __shared__ float wt[2][16];        // softmax weights

  const int tm = blockIdx.x * 16;
  const int t = threadIdx.x;
  const int lane = t & 63;
  const int w = t >> 6;
  const int fr = lane & 15;
  const int kg = lane >> 4;
  const int n0 = w * 2;              // this wave's two 16-col n-tiles

  // ---- FC2: hfc2 = lrelu(hfc1 @ W2^T + b2), K=1024, barrier-free ----
  {
    f32x4 a0 = (f32x4){0.f, 0.f, 0.f, 0.f}, a1 = a0;
    const u16* Ap = hfc1 + (size_t)(tm + fr) * N1P + kg * 8;
    const u16* B0 = W2bf + (size_t)(n0 * 16 + fr) * N1P + kg * 8;
    const u16* B1 = B0 + (size_t)16 * N1P;
#pragma unroll 8
    for (int kt = 0; kt < N1P / 32; ++kt) {
      bf16x8 af = *(const bf16x8*)(Ap + kt * 32);
      bf16x8 f0 = *(const bf16x8*)(B0 + kt * 32);
      bf16x8 f1 = *(const bf16x8*)(B1 + kt * 32);
      a0 = __builtin_amdgcn_mfma_f32_16x16x32_bf16(af, f0, a0, 0, 0, 0);
      a1 = __builtin_amdgcn_mfma_f32_16x16x32_bf16(af, f1, a1, 0, 0, 0);
    }
    // epilogue: C layout col=fr(+16n), row=kg*4+j
#pragma unroll
    for (int n = 0; n < 2; ++n) {
      int col = (n0 + n) * 16 + fr;
      float bv = (col < N2R) ? b2[col] : 0.f;
      f32x4 v = n == 0 ? a0 : a1;
      f32x4 o;
#pragma unroll
      for (int j = 0; j < 4; ++j) {
        float x = v[j] + bv;
        o[j] = x > 0.f ? x : 0.01f * x;
      }
      *(f32x4*)&H16[col][kg * 4] = o;
    }
  }
  __syncthreads();

  // ---- G/E gate sections: tanh(ld @ W^T + b), dot with H16 ----
#pragma unroll 1
  for (int sec = 0; sec < 2; ++sec) {
    const float* ld = sec == 0 ? ldg : lde;
    const u16* Wb = sec == 0 ? Wgbf : Webf;
    const float* bb = sec == 0 ? bg : be;

    f32x4 a0 = (f32x4){0.f, 0.f, 0.f, 0.f}, a1 = a0;
    const float* Ap = ld + (size_t)(tm + fr) * DG + kg * 8;
    const u16* B0 = Wb + (size_t)(n0 * 16 + fr) * DG + kg * 8;
    const u16* B1 = B0 + (size_t)16 * DG;
#pragma unroll 4
    for (int kt = 0; kt < DG / 32; ++kt) {
      float4 v0 = *(const float4*)(Ap + kt * 32);
      float4 v1 = *(const float4*)(Ap + kt * 32 + 4);
      bf16x8 af;
      af[0] = (short)f2b(v0.x); af[1] = (short)f2b(v0.y);
      af[2] = (short)f2b(v0.z); af[3] = (short)f2b(v0.w);
      af[4] = (short)f2b(v1.x); af[5] = (short)f2b(v1.y);
      af[6] = (short)f2b(v1.z); af[7] = (short)f2b(v1.w);
      bf16x8 f0 = *(const bf16x8*)(B0 + kt * 32);
      bf16x8 f1 = *(const bf16x8*)(B1 + kt * 32);
      a0 = __builtin_amdgcn_mfma_f32_16x16x32_bf16(af, f0, a0, 0, 0, 0);
      a1 = __builtin_amdgcn_mfma_f32_16x16x32_bf16(af, f1, a1, 0, 0, 0);
    }
    // tanh + dot with H16 over this wave's 32 cols
    float dv[4] = {0.f, 0.f, 0.f, 0.f};
#pragma unroll
    for (int n = 0; n < 2; ++n) {
      int col = (n0 + n) * 16 + fr;
      float bv = (col < N2R) ? bb[col] : 0.f;
      f32x4 v = n == 0 ? a0 : a1;
      f32x4 h = *(const f32x4*)&H16[col][kg * 4];
#pragma unroll
      for (int j = 0; j < 4; ++j)
        dv[j] += tanh_fast(v[j] + bv) * h[j];
    }
    // reduce over the 16-lane fr group (sums 32 cols per row)
#pragma unroll
    for (int j = 0; j < 4; ++j) {
      float v = dv[j];
      v += __shfl_xor(v, 1);
      v += __shfl_xor(v, 2);
      v += __shfl_xor(v, 4);
      v += __shfl_xor(v, 8);
      dv[j] = v;
    }
    if (fr == 0) {
#pragma unroll
      for (int j = 0; j < 4; ++j) dpart[sec][w][kg * 4 + j] = dv[j];
    }
  }
  __syncthreads();

  // ---- softmax per row ----
  if (t < 16) {
    float ag = dpart[0][0][t] + dpart[0][1][t] + dpart[0][2][t] + dpart[0][3][t];
    float ae = dpart[1][0][t] + dpart[1][1][t] + dpart[1][2][t] + dpart[1][3][t];
    float mm = fmaxf(ag, ae);
    float eg = __expf(ag - mm), eo = __expf(ae - mm);
    float inv = 1.f / (eg + eo);
    wt[0][t] = eg * inv;
    wt[1][t] = eo * inv;
  }
  __syncthreads();

  // ---- scale + write both outputs (coalesced float4) ----
  for (int i = t; i < 16 * (DG / 4); i += 256) {
    int r = i >> 7, c = i & 127;
    float w0 = wt[0][r], w1 = wt[1][r];
    size_t off = (size_t)(tm + r) * DG + c * 4;
    float4 a = *(const float4*)(ldg + off);
    a.x *= w0; a.y *= w0; a.z *= w0; a.w *= w0;
    *(float4*)(out0 + off) = a;
    float4 b = *(const float4*)(lde + off);
    b.x *= w1; b.y *= w1; b.z *= w1; b.w *= w1;
    *(float4*)(out1 + off) = b;
  }
}

extern "C" void kernel_launch(void* const* d_in, const int* in_sizes, int n_in,
                              void* d_out, int out_size, void* d_ws, size_t ws_size,
                              hipStream_t stream) {
  const float* ld_gcn = (const float*)d_in[0];
  const float* ld_enc = (const float*)d_in[1];
  const int*   xi     = (const int*)d_in[2];
  const int*   yi     = (const int*)d_in[3];
  const float* H_emb  = (const float*)d_in[4];
  const float* conv_w = (const float*)d_in[5];
  const float* conv_b = (const float*)d_in[6];
  const float* W1     = (const float*)d_in[7];
  const float* b1     = (const float*)d_in[8];
  const float* W2     = (const float*)d_in[9];
  const float* b2     = (const float*)d_in[10];
  const float* Wg     = (const float*)d_in[11];
  const float* bg     = (const float*)d_in[12];
  const float* We     = (const float*)d_in[13];
  const float* be     = (const float*)d_in[14];

  char* ws = (char*)d_ws;
  size_t off = 0;
  auto alloc = [&](size_t bytes) -> void* {
    void* p = ws + off;
    off = (off + bytes + 255) & ~(size_t)255;
    return p;
  };
  float* Abuf = (float*)alloc(240ull * FDIM * 4);
  float* Bbuf = (float*)alloc(404ull * FDIM * 4);
  u16*   cbf  = (u16*)  alloc((size_t)NROWS * FDIM * 2);
  u16*   W1bf = (u16*)  alloc((size_t)N1P * FDIM * 2);
  u16*   W2bf = (u16*)  alloc((size_t)N2P * N1P * 2);
  u16*   Wgbf = (u16*)  alloc((size_t)N2P * DG * 2);
  u16*   Webf = (u16*)  alloc((size_t)N2P * DG * 2);
  u16*   hfc1 = (u16*)  alloc((size_t)NROWS * N1P * 2);
  if (ws_size < off) return;  // ~101 MB needed

  cvt_pad2_kernel<<<4096, 256, 0, stream>>>(W1, W1bf, N1R, FDIM, N1P, FDIM);
  cvt_pad2_kernel<<<512, 256, 0, stream>>>(W2, W2bf, N2R, N1R, N2P, N1P);
  cvt_pad2_kernel<<<256, 256, 0, stream>>>(Wg, Wgbf, N2R, DG, N2P, DG);
  cvt_pad2_kernel<<<256, 256, 0, stream>>>(We, Webf, N2R, DG, N2P, DG);
  precomp_ab_kernel<<<644, 256, 0, stream>>>(H_emb, conv_w, conv_b, Abuf, Bbuf);
  conv_combine_kernel<<<NROWS, 256, 0, stream>>>(Abuf, Bbuf, xi, yi, cbf);

  fc1_kernel<<<dim3((NROWS / 128) * (N1P / 128)), 256, 0, stream>>>(
      cbf, W1bf, b1, N1R, hfc1, FDIM, N1P, N1P / 128);

  float* out0 = (float*)d_out;
  float* out1 = out0 + (size_t)NROWS * DG;
  tail_kernel<<<NROWS / 16, 256, 0, stream>>>(
      hfc1, W2bf, b2, ld_gcn, ld_enc, Wgbf, bg, Webf, be, out0, out1);
}

// Round 5
// 196.565 us; speedup vs baseline: 1.3052x; 1.1180x over previous
//
#include <hip/hip_runtime.h>
#include <hip/hip_bf16.h>

typedef unsigned short u16;
typedef short bf16x8 __attribute__((ext_vector_type(8)));
typedef float f32x4 __attribute__((ext_vector_type(4)));

#define NROWS 8192
#define EMBD  1140
#define FDIM  3968   // 32*124 = 62*64
#define N1R   1000
#define N1P   1024
#define N2R   100
#define N2P   128
#define DG    512

__device__ inline u16 f2b(float f) {
  __hip_bfloat16 h = __float2bfloat16(f);
  return *reinterpret_cast<u16*>(&h);
}

__device__ inline float tanh_fast(float x) {
  float ax = fabsf(x);
  float t = __expf(-2.f * ax);
  float r = (1.f - t) / (1.f + t);
  return x < 0.f ? -r : r;
}

// async global->LDS, 16B per lane; LDS dest = wave-uniform base + lane*16
__device__ inline void gld16(const void* g, void* l) {
  __builtin_amdgcn_global_load_lds(
      (const __attribute__((address_space(1))) unsigned int*)g,
      (__attribute__((address_space(3))) unsigned int*)l, 16, 0, 0);
}

// ---------------- prep: ALL weight conversions + separable-conv precompute, one launch ----------------
// blocks [0,1984): W1 1024x3968 cvt; [1984,2048): W2 128x1024; [2048,2080): Wg; [2080,2112): We;
// [2112,2756): precomp_ab (644 embedding rows).
__global__ __launch_bounds__(256) void prep_kernel(
    const float* __restrict__ W1, const float* __restrict__ W2,
    const float* __restrict__ Wg, const float* __restrict__ We,
    const float* __restrict__ H_emb, const float* __restrict__ conv_w,
    const float* __restrict__ conv_b,
    u16* __restrict__ W1bf, u16* __restrict__ W2bf,
    u16* __restrict__ Wgbf, u16* __restrict__ Webf,
    float* __restrict__ Abuf, float* __restrict__ Bbuf) {
  const int b = blockIdx.x;
  const int t = threadIdx.x;
  if (b < 2112) {
    const float* src;
    u16* dst;
    int row, c8, realRow, realCol;
    if (b < 1984) {            // W1: chunks of 8 over 1024x3968
      int id = b * 256 + t;
      row = id / 496; c8 = (id - row * 496) * 8;
      src = W1 + (size_t)row * FDIM + c8;
      dst = W1bf + (size_t)row * FDIM + c8;
      realRow = N1R; realCol = FDIM;
    } else if (b < 2048) {     // W2: 128x1024, realK=1000
      int id = (b - 1984) * 256 + t;
      row = id >> 7; c8 = (id & 127) * 8;
      src = W2 + (size_t)row * N1R + c8;
      dst = W2bf + (size_t)row * N1P + c8;
      realRow = N2R; realCol = N1R;
    } else if (b < 2080) {     // Wg: 128x512
      int id = (b - 2048) * 256 + t;
      row = id >> 6; c8 = (id & 63) * 8;
      src = Wg + (size_t)row * DG + c8;
      dst = Wgbf + (size_t)row * DG + c8;
      realRow = N2R; realCol = DG;
    } else {                   // We: 128x512
      int id = (b - 2080) * 256 + t;
      row = id >> 6; c8 = (id & 63) * 8;
      src = We + (size_t)row * DG + c8;
      dst = Webf + (size_t)row * DG + c8;
      realRow = N2R; realCol = DG;
    }
    bf16x8 o = (bf16x8){0, 0, 0, 0, 0, 0, 0, 0};
    if (row < realRow && c8 < realCol) {
#pragma unroll
      for (int j = 0; j < 8; ++j) o[j] = (short)f2b(src[j]);
    }
    *(bf16x8*)dst = o;
    return;
  }
  // ---- precomp_ab segment ----
  __shared__ float se[EMBD];
  __shared__ float sw[32 * 25];
  __shared__ float sb[32];
  const int eb = b - 2112;   // 0..643
  bool isA = eb < 240;
  const float* emb = H_emb + (size_t)eb * EMBD;
  float* outp = isA ? (Abuf + (size_t)eb * FDIM) : (Bbuf + (size_t)(eb - 240) * FDIM);
  for (int i = t; i < EMBD; i += 256) se[i] = emb[i];
  int kh = isA ? 0 : 1;
  for (int i = t; i < 800; i += 256) {
    int o = i / 25, kw = i - o * 25;
    sw[i] = conv_w[o * 50 + kh * 25 + kw];
  }
  if (t < 32) sb[t] = isA ? conv_b[t] : 0.f;
  __syncthreads();
  for (int f = t; f < FDIM; f += 256) {
    int o = f / 124, wpos = f - o * 124;
    const float* e = se + wpos * 9;
    const float* wp = sw + o * 25;
    float acc = sb[o];
#pragma unroll
    for (int kw = 0; kw < 25; ++kw) acc += wp[kw] * e[kw];
    outp[f] = acc;
  }
}

// c[r][f] = lrelu(A[x[r]][f] + B[y[r]][f])  -> bf16
__global__ __launch_bounds__(256) void conv_combine_kernel(
    const float* __restrict__ Abuf, const float* __restrict__ Bbuf,
    const int* __restrict__ xi, const int* __restrict__ yi, u16* __restrict__ cbf) {
  int r = blockIdx.x;
  const float4* pa = (const float4*)(Abuf + (size_t)xi[r] * FDIM);
  const float4* pb = (const float4*)(Bbuf + (size_t)yi[r] * FDIM);
  u16* out = cbf + (size_t)r * FDIM;
  for (int i = threadIdx.x; i < FDIM / 4; i += 256) {
    float4 a = pa[i], b = pb[i];
    float v0 = a.x + b.x, v1 = a.y + b.y, v2 = a.z + b.z, v3 = a.w + b.w;
    v0 = v0 > 0.f ? v0 : 0.01f * v0;
    v1 = v1 > 0.f ? v1 : 0.01f * v1;
    v2 = v2 > 0.f ? v2 : 0.01f * v2;
    v3 = v3 > 0.f ? v3 : 0.01f * v3;
    ushort4 o;
    o.x = f2b(v0); o.y = f2b(v1); o.z = f2b(v2); o.w = f2b(v3);
    *(ushort4*)(out + i * 4) = o;
  }
}

// ---------------- FC1: 128x128 tile, BK=64, double-buffered gld, 2-phase pipeline ----------------
// Swizzle (rule 21, both sides): LDS[row][u16unit u] = Global[row][u ^ (row&7)].
// Stage: lane l in chunk c -> row c*8+(l>>3); linear LDS unit (l&7); global unit (l&7)^(l>>3).
// Read: fragment for k-unit (ks*4+kg) at LDS unit (ks*4+kg)^(fr&7)  [row&7 == fr&7].
__global__ __launch_bounds__(256) void fc1_kernel(
    const u16* __restrict__ A, const u16* __restrict__ B,
    const float* __restrict__ bias, int realN,
    u16* __restrict__ C, int K, int ldc, int nTilesX) {
  const int nwg = gridDim.x;
  const int cpx = nwg >> 3;
  const int bid = blockIdx.x;
  const int wg = (bid & 7) * cpx + (bid >> 3);   // XCD gets contiguous wg chunk
  const int tm = (wg / nTilesX) * 128;
  const int tn = (wg % nTilesX) * 128;

  __shared__ u16 As[2][8192];   // [buf][128 rows x 64 cols]
  __shared__ u16 Bs[2][8192];
  const int t = threadIdx.x;
  const int lane = t & 63;
  const int w = t >> 6;
  const int wr = (w >> 1) * 64, wc = (w & 1) * 64;
  const int fr = lane & 15;
  const int kg = lane >> 4;

  const int srow = lane >> 3;                 // 0..7 within 8-row chunk
  const int su = ((lane & 7) ^ srow) * 8;     // pre-swizzled global u16-col
  const u16* gA[4];
  const u16* gB[4];
  int ldsOff[4];
#pragma unroll
  for (int i = 0; i < 4; ++i) {
    const int c = w + i * 4;                  // chunk 0..15, 8 rows each
    gA[i] = A + (size_t)(tm + c * 8 + srow) * K + su;
    gB[i] = B + (size_t)(tn + c * 8 + srow) * K + su;
    ldsOff[i] = c * 512;                      // u16 offset of chunk
  }

  f32x4 acc[4][4];
#pragma unroll
  for (int m = 0; m < 4; ++m)
#pragma unroll
    for (int n = 0; n < 4; ++n) acc[m][n] = (f32x4){0.f, 0.f, 0.f, 0.f};

  const int nk = K >> 6;   // BK=64
  // prologue: stage tile 0 into buf 0
#pragma unroll
  for (int i = 0; i < 4; ++i) {
    gld16(gA[i], &As[0][ldsOff[i]]);
    gld16(gB[i], &Bs[0][ldsOff[i]]);
  }
  __syncthreads();   // drains vmcnt

  for (int kt = 0; kt < nk; ++kt) {
    const int cb = kt & 1;
    if (kt + 1 < nk) {   // issue next-tile loads FIRST (latency hides under compute)
      const int ko = (kt + 1) << 6;
#pragma unroll
      for (int i = 0; i < 4; ++i) {
        gld16(gA[i] + ko, &As[cb ^ 1][ldsOff[i]]);
        gld16(gB[i] + ko, &Bs[cb ^ 1][ldsOff[i]]);
      }
    }
    __builtin_amdgcn_sched_barrier(0);   // pin: stage-issue stays above compute
#pragma unroll
    for (int ks = 0; ks < 2; ++ks) {
      const int un = ((ks * 4 + kg) ^ (fr & 7)) << 4;   // byte offset of swizzled 16B unit
      bf16x8 af[4], bff[4];
#pragma unroll
      for (int m = 0; m < 4; ++m)
        af[m] = *(const bf16x8*)((const char*)As[cb] + (wr + m * 16 + fr) * 128 + un);
#pragma unroll
      for (int n = 0; n < 4; ++n)
        bff[n] = *(const bf16x8*)((const char*)Bs[cb] + (wc + n * 16 + fr) * 128 + un);
#pragma unroll
      for (int m = 0; m < 4; ++m)
#pragma unroll
        for (int n = 0; n < 4; ++n)
          acc[m][n] = __builtin_amdgcn_mfma_f32_16x16x32_bf16(af[m], bff[n], acc[m][n], 0, 0, 0);
    }
    __syncthreads();   // waits this iter's prefetch (vmcnt) + guards buffer swap
  }

  // epilogue: C/D layout col=lane&15, row=(lane>>4)*4+j  [m89/m91]
#pragma unroll
  for (int n = 0; n < 4; ++n) {
    int col = tn + wc + n * 16 + fr;
    float bv = (col < realN) ? bias[col] : 0.f;
#pragma unroll
    for (int m = 0; m < 4; ++m) {
#pragma unroll
      for (int j = 0; j < 4; ++j) {
        int row = tm + wr + m * 16 + kg * 4 + j;
        float v = acc[m][n][j] + bv;
        v = v > 0.f ? v : 0.01f * v;
        C[(size_t)row * ldc + col] = f2b(v);
      }
    }
  }
}

// ---------------- fused tail: barrier-free GEMM sections, 512 blocks ----------------
__global__ __launch_bounds__(256) void tail_kernel(
    const u16* __restrict__ hfc1, const u16* __restrict__ W2bf, const float* __restrict__ b2,
    const float* __restrict__ ldg, const float* __restrict__ lde,
    const u16* __restrict__ Wgbf, const float* __restrict__ bg,
    const u16* __restrict__ Webf, const float* __restrict__ be,
    float* __restrict__ out0, float* __restrict__ out1) {
  __shared__ float H16[N2P][16];     // [col][row] hfc2 tile
  __shared__ float dpart[2][4][16];  // [sec][wave][row] partial dots
  __shared__ float wt[2][16];        // softmax weights

  const int tm = blockIdx.x * 16;
  const int t = threadIdx.x;
  const int lane = t & 63;
  const int w = t >> 6;
  const int fr = lane & 15;
  const int kg = lane >> 4;
  const int n0 = w * 2;              // this wave's two 16-col n-tiles

  // ---- FC2: hfc2 = lrelu(hfc1 @ W2^T + b2), K=1024, barrier-free ----
  {
    f32x4 a0 = (f32x4){0.f, 0.f, 0.f, 0.f}, a1 = a0;
    const u16* Ap = hfc1 + (size_t)(tm + fr) * N1P + kg * 8;
    const u16* B0 = W2bf + (size_t)(n0 * 16 + fr) * N1P + kg * 8;
    const u16* B1 = B0 + (size_t)16 * N1P;
#pragma unroll 8
    for (int kt = 0; kt < N1P / 32; ++kt) {
      bf16x8 af = *(const bf16x8*)(Ap + kt * 32);
      bf16x8 f0 = *(const bf16x8*)(B0 + kt * 32);
      bf16x8 f1 = *(const bf16x8*)(B1 + kt * 32);
      a0 = __builtin_amdgcn_mfma_f32_16x16x32_bf16(af, f0, a0, 0, 0, 0);
      a1 = __builtin_amdgcn_mfma_f32_16x16x32_bf16(af, f1, a1, 0, 0, 0);
    }
#pragma unroll
    for (int n = 0; n < 2; ++n) {
      int col = (n0 + n) * 16 + fr;
      float bv = (col < N2R) ? b2[col] : 0.f;
      f32x4 v = n == 0 ? a0 : a1;
      f32x4 o;
#pragma unroll
      for (int j = 0; j < 4; ++j) {
        float x = v[j] + bv;
        o[j] = x > 0.f ? x : 0.01f * x;
      }
      *(f32x4*)&H16[col][kg * 4] = o;
    }
  }
  __syncthreads();

  // ---- G/E gate sections: tanh(ld @ W^T + b), dot with H16 ----
#pragma unroll 1
  for (int sec = 0; sec < 2; ++sec) {
    const float* ld = sec == 0 ? ldg : lde;
    const u16* Wb = sec == 0 ? Wgbf : Webf;
    const float* bb = sec == 0 ? bg : be;

    f32x4 a0 = (f32x4){0.f, 0.f, 0.f, 0.f}, a1 = a0;
    const float* Ap = ld + (size_t)(tm + fr) * DG + kg * 8;
    const u16* B0 = Wb + (size_t)(n0 * 16 + fr) * DG + kg * 8;
    const u16* B1 = B0 + (size_t)16 * DG;
#pragma unroll 4
    for (int kt = 0; kt < DG / 32; ++kt) {
      float4 v0 = *(const float4*)(Ap + kt * 32);
      float4 v1 = *(const float4*)(Ap + kt * 32 + 4);
      bf16x8 af;
      af[0] = (short)f2b(v0.x); af[1] = (short)f2b(v0.y);
      af[2] = (short)f2b(v0.z); af[3] = (short)f2b(v0.w);
      af[4] = (short)f2b(v1.x); af[5] = (short)f2b(v1.y);
      af[6] = (short)f2b(v1.z); af[7] = (short)f2b(v1.w);
      bf16x8 f0 = *(const bf16x8*)(B0 + kt * 32);
      bf16x8 f1 = *(const bf16x8*)(B1 + kt * 32);
      a0 = __builtin_amdgcn_mfma_f32_16x16x32_bf16(af, f0, a0, 0, 0, 0);
      a1 = __builtin_amdgcn_mfma_f32_16x16x32_bf16(af, f1, a1, 0, 0, 0);
    }
    float dv[4] = {0.f, 0.f, 0.f, 0.f};
#pragma unroll
    for (int n = 0; n < 2; ++n) {
      int col = (n0 + n) * 16 + fr;
      float bv = (col < N2R) ? bb[col] : 0.f;
      f32x4 v = n == 0 ? a0 : a1;
      f32x4 h = *(const f32x4*)&H16[col][kg * 4];
#pragma unroll
      for (int j = 0; j < 4; ++j)
        dv[j] += tanh_fast(v[j] + bv) * h[j];
    }
#pragma unroll
    for (int j = 0; j < 4; ++j) {
      float v = dv[j];
      v += __shfl_xor(v, 1);
      v += __shfl_xor(v, 2);
      v += __shfl_xor(v, 4);
      v += __shfl_xor(v, 8);
      dv[j] = v;
    }
    if (fr == 0) {
#pragma unroll
      for (int j = 0; j < 4; ++j) dpart[sec][w][kg * 4 + j] = dv[j];
    }
  }
  __syncthreads();

  // ---- softmax per row ----
  if (t < 16) {
    float ag = dpart[0][0][t] + dpart[0][1][t] + dpart[0][2][t] + dpart[0][3][t];
    float ae = dpart[1][0][t] + dpart[1][1][t] + dpart[1][2][t] + dpart[1][3][t];
    float mm = fmaxf(ag, ae);
    float eg = __expf(ag - mm), eo = __expf(ae - mm);
    float inv = 1.f / (eg + eo);
    wt[0][t] = eg * inv;
    wt[1][t] = eo * inv;
  }
  __syncthreads();

  // ---- scale + write both outputs (coalesced float4) ----
  for (int i = t; i < 16 * (DG / 4); i += 256) {
    int r = i >> 7, c = i & 127;
    float w0 = wt[0][r], w1 = wt[1][r];
    size_t off = (size_t)(tm + r) * DG + c * 4;
    float4 a = *(const float4*)(ldg + off);
    a.x *= w0; a.y *= w0; a.z *= w0; a.w *= w0;
    *(float4*)(out0 + off) = a;
    float4 b = *(const float4*)(lde + off);
    b.x *= w1; b.y *= w1; b.z *= w1; b.w *= w1;
    *(float4*)(out1 + off) = b;
  }
}

extern "C" void kernel_launch(void* const* d_in, const int* in_sizes, int n_in,
                              void* d_out, int out_size, void* d_ws, size_t ws_size,
                              hipStream_t stream) {
  const float* ld_gcn = (const float*)d_in[0];
  const float* ld_enc = (const float*)d_in[1];
  const int*   xi     = (const int*)d_in[2];
  const int*   yi     = (const int*)d_in[3];
  const float* H_emb  = (const float*)d_in[4];
  const float* conv_w = (const float*)d_in[5];
  const float* conv_b = (const float*)d_in[6];
  const float* W1     = (const float*)d_in[7];
  const float* b1     = (const float*)d_in[8];
  const float* W2     = (const float*)d_in[9];
  const float* b2     = (const float*)d_in[10];
  const float* Wg     = (const float*)d_in[11];
  const float* bg     = (const float*)d_in[12];
  const float* We     = (const float*)d_in[13];
  const float* be     = (const float*)d_in[14];

  char* ws = (char*)d_ws;
  size_t off = 0;
  auto alloc = [&](size_t bytes) -> void* {
    void* p = ws + off;
    off = (off + bytes + 255) & ~(size_t)255;
    return p;
  };
  float* Abuf = (float*)alloc(240ull * FDIM * 4);
  float* Bbuf = (float*)alloc(404ull * FDIM * 4);
  u16*   cbf  = (u16*)  alloc((size_t)NROWS * FDIM * 2);
  u16*   W1bf = (u16*)  alloc((size_t)N1P * FDIM * 2);
  u16*   W2bf = (u16*)  alloc((size_t)N2P * N1P * 2);
  u16*   Wgbf = (u16*)  alloc((size_t)N2P * DG * 2);
  u16*   Webf = (u16*)  alloc((size_t)N2P * DG * 2);
  u16*   hfc1 = (u16*)  alloc((size_t)NROWS * N1P * 2);
  if (ws_size < off) return;  // ~101 MB needed

  prep_kernel<<<2756, 256, 0, stream>>>(W1, W2, Wg, We, H_emb, conv_w, conv_b,
                                        W1bf, W2bf, Wgbf, Webf, Abuf, Bbuf);
  conv_combine_kernel<<<NROWS, 256, 0, stream>>>(Abuf, Bbuf, xi, yi, cbf);

  fc1_kernel<<<dim3((NROWS / 128) * (N1P / 128)), 256, 0, stream>>>(
      cbf, W1bf, b1, N1R, hfc1, FDIM, N1P, N1P / 128);

  float* out0 = (float*)d_out;
  float* out1 = out0 + (size_t)NROWS * DG;
  tail_kernel<<<NROWS / 16, 256, 0, stream>>>(
      hfc1, W2bf, b2, ld_gcn, ld_enc, Wgbf, bg, Webf, be, out0, out1);
}

// Round 6
// 189.590 us; speedup vs baseline: 1.3533x; 1.0368x over previous
//
#include <hip/hip_runtime.h>
#include <hip/hip_bf16.h>

typedef unsigned short u16;
typedef short bf16x8 __attribute__((ext_vector_type(8)));
typedef float f32x4 __attribute__((ext_vector_type(4)));

#define NROWS 8192
#define EMBD  1140
#define FDIM  3968   // 32*124 = 62*64
#define N1R   1000
#define N1P   1024
#define N2R   100
#define N2P   128
#define DG    512

__device__ inline u16 f2b(float f) {
  __hip_bfloat16 h = __float2bfloat16(f);
  return *reinterpret_cast<u16*>(&h);
}

__device__ inline float b2f(u16 u) {
  unsigned v = (unsigned)u << 16;
  union { unsigned u; float f; } c;
  c.u = v;
  return c.f;
}

__device__ inline float tanh_fast(float x) {
  float ax = fabsf(x);
  float t = __expf(-2.f * ax);
  float r = (1.f - t) / (1.f + t);
  return x < 0.f ? -r : r;
}

// async global->LDS, 16B per lane; LDS dest = wave-uniform base + lane*16
__device__ inline void gld16(const void* g, void* l) {
  __builtin_amdgcn_global_load_lds(
      (const __attribute__((address_space(1))) unsigned int*)g,
      (__attribute__((address_space(3))) unsigned int*)l, 16, 0, 0);
}

// ---------------- prep: ALL weight conversions + separable-conv precompute ----------------
// blocks [0,1984): W1; [1984,2048): W2; [2048,2080): Wg; [2080,2112): We; [2112,2756): precomp_ab.
__global__ __launch_bounds__(256) void prep_kernel(
    const float* __restrict__ W1, const float* __restrict__ W2,
    const float* __restrict__ Wg, const float* __restrict__ We,
    const float* __restrict__ H_emb, const float* __restrict__ conv_w,
    const float* __restrict__ conv_b,
    u16* __restrict__ W1bf, u16* __restrict__ W2bf,
    u16* __restrict__ Wgbf, u16* __restrict__ Webf,
    u16* __restrict__ Abuf, u16* __restrict__ Bbuf) {
  const int b = blockIdx.x;
  const int t = threadIdx.x;
  if (b < 2112) {
    const float* src;
    u16* dst;
    int row, c8, realRow, realCol;
    if (b < 1984) {            // W1: 1024x3968
      int id = b * 256 + t;
      row = id / 496; c8 = (id - row * 496) * 8;
      src = W1 + (size_t)row * FDIM + c8;
      dst = W1bf + (size_t)row * FDIM + c8;
      realRow = N1R; realCol = FDIM;
    } else if (b < 2048) {     // W2: 128x1024, realK=1000
      int id = (b - 1984) * 256 + t;
      row = id >> 7; c8 = (id & 127) * 8;
      src = W2 + (size_t)row * N1R + c8;
      dst = W2bf + (size_t)row * N1P + c8;
      realRow = N2R; realCol = N1R;
    } else if (b < 2080) {     // Wg: 128x512
      int id = (b - 2048) * 256 + t;
      row = id >> 6; c8 = (id & 63) * 8;
      src = Wg + (size_t)row * DG + c8;
      dst = Wgbf + (size_t)row * DG + c8;
      realRow = N2R; realCol = DG;
    } else {                   // We: 128x512
      int id = (b - 2080) * 256 + t;
      row = id >> 6; c8 = (id & 63) * 8;
      src = We + (size_t)row * DG + c8;
      dst = Webf + (size_t)row * DG + c8;
      realRow = N2R; realCol = DG;
    }
    bf16x8 o = (bf16x8){0, 0, 0, 0, 0, 0, 0, 0};
    if (row < realRow && c8 < realCol) {
#pragma unroll
      for (int j = 0; j < 8; ++j) o[j] = (short)f2b(src[j]);
    }
    *(bf16x8*)dst = o;
    return;
  }
  // ---- precomp_ab segment (bf16 output) ----
  __shared__ float se[EMBD];
  __shared__ float sw[32 * 25];
  __shared__ float sb[32];
  const int eb = b - 2112;   // 0..643
  bool isA = eb < 240;
  const float* emb = H_emb + (size_t)eb * EMBD;
  u16* outp = isA ? (Abuf + (size_t)eb * FDIM) : (Bbuf + (size_t)(eb - 240) * FDIM);
  for (int i = t; i < EMBD; i += 256) se[i] = emb[i];
  int kh = isA ? 0 : 1;
  for (int i = t; i < 800; i += 256) {
    int o = i / 25, kw = i - o * 25;
    sw[i] = conv_w[o * 50 + kh * 25 + kw];
  }
  if (t < 32) sb[t] = isA ? conv_b[t] : 0.f;
  __syncthreads();
  for (int f = t; f < FDIM; f += 256) {
    int o = f / 124, wpos = f - o * 124;
    const float* e = se + wpos * 9;
    const float* wp = sw + o * 25;
    float acc = sb[o];
#pragma unroll
    for (int kw = 0; kw < 25; ++kw) acc += wp[kw] * e[kw];
    outp[f] = f2b(acc);
  }
}

// c[r][f] = lrelu(A[x[r]][f] + B[y[r]][f])  -> bf16  (A/B now bf16: half the L3 reads)
__global__ __launch_bounds__(256) void conv_combine_kernel(
    const u16* __restrict__ Abuf, const u16* __restrict__ Bbuf,
    const int* __restrict__ xi, const int* __restrict__ yi, u16* __restrict__ cbf) {
  int r = blockIdx.x;
  const bf16x8* pa = (const bf16x8*)(Abuf + (size_t)xi[r] * FDIM);
  const bf16x8* pb = (const bf16x8*)(Bbuf + (size_t)yi[r] * FDIM);
  bf16x8* out = (bf16x8*)(cbf + (size_t)r * FDIM);
  for (int i = threadIdx.x; i < FDIM / 8; i += 256) {
    bf16x8 a = pa[i], b = pb[i];
    bf16x8 o;
#pragma unroll
    for (int j = 0; j < 8; ++j) {
      float v = b2f((u16)a[j]) + b2f((u16)b[j]);
      v = v > 0.f ? v : 0.01f * v;
      o[j] = (short)f2b(v);
    }
    out[i] = o;
  }
}

// ---------------- FC1: 128x128 tile, BK=64, 2-deep counted-vmcnt pipeline ----------------
// Swizzle (rule 21, both sides): LDS[row][u16unit u] = Global[row][u ^ (row&7)].
// Pipeline: tiles kt+1 (ready-next) and kt+2 (in flight) overlap compute(kt);
// s_waitcnt vmcnt(8) retires exactly the next tile's 8 per-wave loads (T4, m218).
__global__ __launch_bounds__(256) void fc1_kernel(
    const u16* __restrict__ A, const u16* __restrict__ B,
    const float* __restrict__ bias, int realN,
    u16* __restrict__ C, int K, int ldc, int nTilesX) {
  const int nwg = gridDim.x;
  const int cpx = nwg >> 3;
  const int bid = blockIdx.x;
  const int wg = (bid & 7) * cpx + (bid >> 3);   // XCD gets contiguous wg chunk
  const int tm = (wg / nTilesX) * 128;
  const int tn = (wg % nTilesX) * 128;

  __shared__ u16 As[2][8192];   // [buf][128 rows x 64 cols]
  __shared__ u16 Bs[2][8192];
  const int t = threadIdx.x;
  const int lane = t & 63;
  const int w = t >> 6;
  const int wr = (w >> 1) * 64, wc = (w & 1) * 64;
  const int fr = lane & 15;
  const int kg = lane >> 4;

  const int srow = lane >> 3;                 // 0..7 within 8-row chunk
  const int su = ((lane & 7) ^ srow) * 8;     // pre-swizzled global u16-col
  const u16* gA[4];
  const u16* gB[4];
  int ldsOff[4];
#pragma unroll
  for (int i = 0; i < 4; ++i) {
    const int c = w + i * 4;                  // chunk 0..15, 8 rows each
    gA[i] = A + (size_t)(tm + c * 8 + srow) * K + su;
    gB[i] = B + (size_t)(tn + c * 8 + srow) * K + su;
    ldsOff[i] = c * 512;                      // u16 offset of chunk
  }

#define STAGE(kt_, cb_) do { \
    const int ko_ = (kt_) << 6; \
    _Pragma("unroll") for (int i = 0; i < 4; ++i) { \
      gld16(gA[i] + ko_, &As[cb_][ldsOff[i]]); \
      gld16(gB[i] + ko_, &Bs[cb_][ldsOff[i]]); \
    } \
  } while (0)

  f32x4 acc[4][4];
#pragma unroll
  for (int m = 0; m < 4; ++m)
#pragma unroll
    for (int n = 0; n < 4; ++n) acc[m][n] = (f32x4){0.f, 0.f, 0.f, 0.f};

  const int nk = K >> 6;   // BK=64, nk=62
  // prologue: tiles 0 and 1 in flight; retire tile 0 (leave tile 1's 8 out)
  STAGE(0, 0);
  STAGE(1, 1);
  asm volatile("s_waitcnt vmcnt(8)" ::: "memory");
  __builtin_amdgcn_sched_barrier(0);
  __builtin_amdgcn_s_barrier();
  __builtin_amdgcn_sched_barrier(0);

  for (int kt = 0; kt < nk; ++kt) {
    const int cb = kt & 1;
#pragma unroll
    for (int ks = 0; ks < 2; ++ks) {
      const int un = ((ks * 4 + kg) ^ (fr & 7)) << 4;   // byte offset of swizzled 16B unit
      bf16x8 af[4], bff[4];
#pragma unroll
      for (int m = 0; m < 4; ++m)
        af[m] = *(const bf16x8*)((const char*)As[cb] + (wr + m * 16 + fr) * 128 + un);
#pragma unroll
      for (int n = 0; n < 4; ++n)
        bff[n] = *(const bf16x8*)((const char*)Bs[cb] + (wc + n * 16 + fr) * 128 + un);
#pragma unroll
      for (int m = 0; m < 4; ++m)
#pragma unroll
        for (int n = 0; n < 4; ++n)
          acc[m][n] = __builtin_amdgcn_mfma_f32_16x16x32_bf16(af[m], bff[n], acc[m][n], 0, 0, 0);
    }
    if (kt + 1 == nk) break;
    // all fragment ds_reads retired (their MFMAs consumed them above)
    __builtin_amdgcn_s_barrier();            // all waves done reading buf[cb]
    __builtin_amdgcn_sched_barrier(0);
    if (kt + 2 < nk) {
      STAGE(kt + 2, cb);                     // overwrite freed buffer
      asm volatile("s_waitcnt vmcnt(8)" ::: "memory");  // retire tile kt+1's 8
    } else {
      asm volatile("s_waitcnt vmcnt(0)" ::: "memory");  // last tile: full drain
    }
    __builtin_amdgcn_sched_barrier(0);
    __builtin_amdgcn_s_barrier();            // tile kt+1 visible to all waves
    __builtin_amdgcn_sched_barrier(0);
  }
#undef STAGE

  // epilogue: C/D layout col=lane&15, row=(lane>>4)*4+j  [m89/m91]
#pragma unroll
  for (int n = 0; n < 4; ++n) {
    int col = tn + wc + n * 16 + fr;
    float bv = (col < realN) ? bias[col] : 0.f;
#pragma unroll
    for (int m = 0; m < 4; ++m) {
#pragma unroll
      for (int j = 0; j < 4; ++j) {
        int row = tm + wr + m * 16 + kg * 4 + j;
        float v = acc[m][n][j] + bv;
        v = v > 0.f ? v : 0.01f * v;
        C[(size_t)row * ldc + col] = f2b(v);
      }
    }
  }
}

// ---------------- fused tail: barrier-free GEMM sections, 512 blocks ----------------
__global__ __launch_bounds__(256) void tail_kernel(
    const u16* __restrict__ hfc1, const u16* __restrict__ W2bf, const float* __restrict__ b2,
    const float* __restrict__ ldg, const float* __restrict__ lde,
    const u16* __restrict__ Wgbf, const float* __restrict__ bg,
    const u16* __restrict__ Webf, const float* __restrict__ be,
    float* __restrict__ out0, float* __restrict__ out1) {
  __shared__ float H16[N2P][16];     // [col][row] hfc2 tile
  __shared__ float dpart[2][4][16];  // [sec][wave][row] partial dots
  __shared__ float wt[2][16];        // softmax weights

  const int tm = blockIdx.x * 16;
  const int t = threadIdx.x;
  const int lane = t & 63;
  const int w = t >> 6;
  const int fr = lane & 15;
  const int kg = lane >> 4;
  const int n0 = w * 2;              // this wave's two 16-col n-tiles

  // ---- FC2: hfc2 = lrelu(hfc1 @ W2^T + b2), K=1024, barrier-free ----
  {
    f32x4 a0 = (f32x4){0.f, 0.f, 0.f, 0.f}, a1 = a0;
    const u16* Ap = hfc1 + (size_t)(tm + fr) * N1P + kg * 8;
    const u16* B0 = W2bf + (size_t)(n0 * 16 + fr) * N1P + kg * 8;
    const u16* B1 = B0 + (size_t)16 * N1P;
#pragma unroll 8
    for (int kt = 0; kt < N1P / 32; ++kt) {
      bf16x8 af = *(const bf16x8*)(Ap + kt * 32);
      bf16x8 f0 = *(const bf16x8*)(B0 + kt * 32);
      bf16x8 f1 = *(const bf16x8*)(B1 + kt * 32);
      a0 = __builtin_amdgcn_mfma_f32_16x16x32_bf16(af, f0, a0, 0, 0, 0);
      a1 = __builtin_amdgcn_mfma_f32_16x16x32_bf16(af, f1, a1, 0, 0, 0);
    }
#pragma unroll
    for (int n = 0; n < 2; ++n) {
      int col = (n0 + n) * 16 + fr;
      float bv = (col < N2R) ? b2[col] : 0.f;
      f32x4 v = n == 0 ? a0 : a1;
      f32x4 o;
#pragma unroll
      for (int j = 0; j < 4; ++j) {
        float x = v[j] + bv;
        o[j] = x > 0.f ? x : 0.01f * x;
      }
      *(f32x4*)&H16[col][kg * 4] = o;
    }
  }
  __syncthreads();

  // ---- G/E gate sections: tanh(ld @ W^T + b), dot with H16 ----
#pragma unroll 1
  for (int sec = 0; sec < 2; ++sec) {
    const float* ld = sec == 0 ? ldg : lde;
    const u16* Wb = sec == 0 ? Wgbf : Webf;
    const float* bb = sec == 0 ? bg : be;

    f32x4 a0 = (f32x4){0.f, 0.f, 0.f, 0.f}, a1 = a0;
    const float* Ap = ld + (size_t)(tm + fr) * DG + kg * 8;
    const u16* B0 = Wb + (size_t)(n0 * 16 + fr) * DG + kg * 8;
    const u16* B1 = B0 + (size_t)16 * DG;
#pragma unroll 4
    for (int kt = 0; kt < DG / 32; ++kt) {
      float4 v0 = *(const float4*)(Ap + kt * 32);
      float4 v1 = *(const float4*)(Ap + kt * 32 + 4);
      bf16x8 af;
      af[0] = (short)f2b(v0.x); af[1] = (short)f2b(v0.y);
      af[2] = (short)f2b(v0.z); af[3] = (short)f2b(v0.w);
      af[4] = (short)f2b(v1.x); af[5] = (short)f2b(v1.y);
      af[6] = (short)f2b(v1.z); af[7] = (short)f2b(v1.w);
      bf16x8 f0 = *(const bf16x8*)(B0 + kt * 32);
      bf16x8 f1 = *(const bf16x8*)(B1 + kt * 32);
      a0 = __builtin_amdgcn_mfma_f32_16x16x32_bf16(af, f0, a0, 0, 0, 0);
      a1 = __builtin_amdgcn_mfma_f32_16x16x32_bf16(af, f1, a1, 0, 0, 0);
    }
    float dv[4] = {0.f, 0.f, 0.f, 0.f};
#pragma unroll
    for (int n = 0; n < 2; ++n) {
      int col = (n0 + n) * 16 + fr;
      float bv = (col < N2R) ? bb[col] : 0.f;
      f32x4 v = n == 0 ? a0 : a1;
      f32x4 h = *(const f32x4*)&H16[col][kg * 4];
#pragma unroll
      for (int j = 0; j < 4; ++j)
        dv[j] += tanh_fast(v[j] + bv) * h[j];
    }
#pragma unroll
    for (int j = 0; j < 4; ++j) {
      float v = dv[j];
      v += __shfl_xor(v, 1);
      v += __shfl_xor(v, 2);
      v += __shfl_xor(v, 4);
      v += __shfl_xor(v, 8);
      dv[j] = v;
    }
    if (fr == 0) {
#pragma unroll
      for (int j = 0; j < 4; ++j) dpart[sec][w][kg * 4 + j] = dv[j];
    }
  }
  __syncthreads();

  // ---- softmax per row ----
  if (t < 16) {
    float ag = dpart[0][0][t] + dpart[0][1][t] + dpart[0][2][t] + dpart[0][3][t];
    float ae = dpart[1][0][t] + dpart[1][1][t] + dpart[1][2][t] + dpart[1][3][t];
    float mm = fmaxf(ag, ae);
    float eg = __expf(ag - mm), eo = __expf(ae - mm);
    float inv = 1.f / (eg + eo);
    wt[0][t] = eg * inv;
    wt[1][t] = eo * inv;
  }
  __syncthreads();

  // ---- scale + write both outputs (coalesced float4) ----
  for (int i = t; i < 16 * (DG / 4); i += 256) {
    int r = i >> 7, c = i & 127;
    float w0 = wt[0][r], w1 = wt[1][r];
    size_t off = (size_t)(tm + r) * DG + c * 4;
    float4 a = *(const float4*)(ldg + off);
    a.x *= w0; a.y *= w0; a.z *= w0; a.w *= w0;
    *(float4*)(out0 + off) = a;
    float4 b = *(const float4*)(lde + off);
    b.x *= w1; b.y *= w1; b.z *= w1; b.w *= w1;
    *(float4*)(out1 + off) = b;
  }
}

extern "C" void kernel_launch(void* const* d_in, const int* in_sizes, int n_in,
                              void* d_out, int out_size, void* d_ws, size_t ws_size,
                              hipStream_t stream) {
  const float* ld_gcn = (const float*)d_in[0];
  const float* ld_enc = (const float*)d_in[1];
  const int*   xi     = (const int*)d_in[2];
  const int*   yi     = (const int*)d_in[3];
  const float* H_emb  = (const float*)d_in[4];
  const float* conv_w = (const float*)d_in[5];
  const float* conv_b = (const float*)d_in[6];
  const float* W1     = (const float*)d_in[7];
  const float* b1     = (const float*)d_in[8];
  const float* W2     = (const float*)d_in[9];
  const float* b2     = (const float*)d_in[10];
  const float* Wg     = (const float*)d_in[11];
  const float* bg     = (const float*)d_in[12];
  const float* We     = (const float*)d_in[13];
  const float* be     = (const float*)d_in[14];

  char* ws = (char*)d_ws;
  size_t off = 0;
  auto alloc = [&](size_t bytes) -> void* {
    void* p = ws + off;
    off = (off + bytes + 255) & ~(size_t)255;
    return p;
  };
  u16* Abuf = (u16*)alloc(240ull * FDIM * 2);
  u16* Bbuf = (u16*)alloc(404ull * FDIM * 2);
  u16* cbf  = (u16*)alloc((size_t)NROWS * FDIM * 2);
  u16* W1bf = (u16*)alloc((size_t)N1P * FDIM * 2);
  u16* W2bf = (u16*)alloc((size_t)N2P * N1P * 2);
  u16* Wgbf = (u16*)alloc((size_t)N2P * DG * 2);
  u16* Webf = (u16*)alloc((size_t)N2P * DG * 2);
  u16* hfc1 = (u16*)alloc((size_t)NROWS * N1P * 2);
  if (ws_size < off) return;  // ~96 MB needed

  prep_kernel<<<2756, 256, 0, stream>>>(W1, W2, Wg, We, H_emb, conv_w, conv_b,
                                        W1bf, W2bf, Wgbf, Webf, Abuf, Bbuf);
  conv_combine_kernel<<<NROWS, 256, 0, stream>>>(Abuf, Bbuf, xi, yi, cbf);

  fc1_kernel<<<dim3((NROWS / 128) * (N1P / 128)), 256, 0, stream>>>(
      cbf, W1bf, b1, N1R, hfc1, FDIM, N1P, N1P / 128);

  float* out0 = (float*)d_out;
  float* out1 = out0 + (size_t)NROWS * DG;
  tail_kernel<<<NROWS / 16, 256, 0, stream>>>(
      hfc1, W2bf, b2, ld_gcn, ld_enc, Wgbf, bg, Webf, be, out0, out1);
}

// Round 7
// 182.544 us; speedup vs baseline: 1.4055x; 1.0386x over previous
//
#include <hip/hip_runtime.h>
#include <hip/hip_bf16.h>

typedef unsigned short u16;
typedef short bf16x8 __attribute__((ext_vector_type(8)));
typedef float f32x4 __attribute__((ext_vector_type(4)));

#define NROWS 8192
#define EMBD  1140
#define FDIM  3968   // 32*124 = 62*64
#define N1R   1000
#define N1P   1024
#define N2R   100
#define N2P   128
#define DG    512

__device__ inline u16 f2b(float f) {
  __hip_bfloat16 h = __float2bfloat16(f);
  return *reinterpret_cast<u16*>(&h);
}

__device__ inline float b2f(u16 u) {
  unsigned v = (unsigned)u << 16;
  union { unsigned u; float f; } c;
  c.u = v;
  return c.f;
}

__device__ inline float tanh_fast(float x) {
  float ax = fabsf(x);
  float t = __expf(-2.f * ax);
  float r = (1.f - t) / (1.f + t);
  return x < 0.f ? -r : r;
}

// async global->LDS, 16B per lane; LDS dest = wave-uniform base + lane*16
__device__ inline void gld16(const void* g, void* l) {
  __builtin_amdgcn_global_load_lds(
      (const __attribute__((address_space(1))) unsigned int*)g,
      (__attribute__((address_space(3))) unsigned int*)l, 16, 0, 0);
}

// ---------------- prep: ALL weight conversions + separable-conv precompute ----------------
// blocks [0,1984): W1; [1984,2048): W2; [2048,2080): Wg; [2080,2112): We; [2112,2756): precomp_ab.
__global__ __launch_bounds__(256) void prep_kernel(
    const float* __restrict__ W1, const float* __restrict__ W2,
    const float* __restrict__ Wg, const float* __restrict__ We,
    const float* __restrict__ H_emb, const float* __restrict__ conv_w,
    const float* __restrict__ conv_b,
    u16* __restrict__ W1bf, u16* __restrict__ W2bf,
    u16* __restrict__ Wgbf, u16* __restrict__ Webf,
    u16* __restrict__ Abuf, u16* __restrict__ Bbuf) {
  const int b = blockIdx.x;
  const int t = threadIdx.x;
  if (b < 2112) {
    const float* src;
    u16* dst;
    int row, c8, realRow, realCol;
    if (b < 1984) {            // W1: 1024x3968
      int id = b * 256 + t;
      row = id / 496; c8 = (id - row * 496) * 8;
      src = W1 + (size_t)row * FDIM + c8;
      dst = W1bf + (size_t)row * FDIM + c8;
      realRow = N1R; realCol = FDIM;
    } else if (b < 2048) {     // W2: 128x1024, realK=1000
      int id = (b - 1984) * 256 + t;
      row = id >> 7; c8 = (id & 127) * 8;
      src = W2 + (size_t)row * N1R + c8;
      dst = W2bf + (size_t)row * N1P + c8;
      realRow = N2R; realCol = N1R;
    } else if (b < 2080) {     // Wg: 128x512
      int id = (b - 2048) * 256 + t;
      row = id >> 6; c8 = (id & 63) * 8;
      src = Wg + (size_t)row * DG + c8;
      dst = Wgbf + (size_t)row * DG + c8;
      realRow = N2R; realCol = DG;
    } else {                   // We: 128x512
      int id = (b - 2080) * 256 + t;
      row = id >> 6; c8 = (id & 63) * 8;
      src = We + (size_t)row * DG + c8;
      dst = Webf + (size_t)row * DG + c8;
      realRow = N2R; realCol = DG;
    }
    bf16x8 o = (bf16x8){0, 0, 0, 0, 0, 0, 0, 0};
    if (row < realRow && c8 < realCol) {
#pragma unroll
      for (int j = 0; j < 8; ++j) o[j] = (short)f2b(src[j]);
    }
    *(bf16x8*)dst = o;
    return;
  }
  // ---- precomp_ab segment (bf16 output) ----
  __shared__ float se[EMBD];
  __shared__ float sw[32 * 25];
  __shared__ float sb[32];
  const int eb = b - 2112;   // 0..643
  bool isA = eb < 240;
  const float* emb = H_emb + (size_t)eb * EMBD;
  u16* outp = isA ? (Abuf + (size_t)eb * FDIM) : (Bbuf + (size_t)(eb - 240) * FDIM);
  for (int i = t; i < EMBD; i += 256) se[i] = emb[i];
  int kh = isA ? 0 : 1;
  for (int i = t; i < 800; i += 256) {
    int o = i / 25, kw = i - o * 25;
    sw[i] = conv_w[o * 50 + kh * 25 + kw];
  }
  if (t < 32) sb[t] = isA ? conv_b[t] : 0.f;
  __syncthreads();
  for (int f = t; f < FDIM; f += 256) {
    int o = f / 124, wpos = f - o * 124;
    const float* e = se + wpos * 9;
    const float* wp = sw + o * 25;
    float acc = sb[o];
#pragma unroll
    for (int kw = 0; kw < 25; ++kw) acc += wp[kw] * e[kw];
    outp[f] = f2b(acc);
  }
}

// c[r][f] = lrelu(A[x[r]][f] + B[y[r]][f])  -> bf16  (A/B bf16: L2-resident panels)
__global__ __launch_bounds__(256) void conv_combine_kernel(
    const u16* __restrict__ Abuf, const u16* __restrict__ Bbuf,
    const int* __restrict__ xi, const int* __restrict__ yi, u16* __restrict__ cbf) {
  int r = blockIdx.x;
  const bf16x8* pa = (const bf16x8*)(Abuf + (size_t)xi[r] * FDIM);
  const bf16x8* pb = (const bf16x8*)(Bbuf + (size_t)yi[r] * FDIM);
  bf16x8* out = (bf16x8*)(cbf + (size_t)r * FDIM);
  for (int i = threadIdx.x; i < FDIM / 8; i += 256) {
    bf16x8 a = pa[i], b = pb[i];
    bf16x8 o;
#pragma unroll
    for (int j = 0; j < 8; ++j) {
      float v = b2f((u16)a[j]) + b2f((u16)b[j]);
      v = v > 0.f ? v : 0.01f * v;
      o[j] = (short)f2b(v);
    }
    out[i] = o;
  }
}

// ---------------- FC1: 128x128 tile, BK=64, double-buffered gld, 2-phase pipeline ----------------
// (round-5 structure, reverted from the counted-vmcnt experiment which regressed 10 µs)
// Swizzle (rule 21, both sides): LDS[row][u16unit u] = Global[row][u ^ (row&7)].
__global__ __launch_bounds__(256) void fc1_kernel(
    const u16* __restrict__ A, const u16* __restrict__ B,
    const float* __restrict__ bias, int realN,
    u16* __restrict__ C, int K, int ldc, int nTilesX) {
  const int nwg = gridDim.x;
  const int cpx = nwg >> 3;
  const int bid = blockIdx.x;
  const int wg = (bid & 7) * cpx + (bid >> 3);   // XCD gets contiguous wg chunk
  const int tm = (wg / nTilesX) * 128;
  const int tn = (wg % nTilesX) * 128;

  __shared__ u16 As[2][8192];   // [buf][128 rows x 64 cols]
  __shared__ u16 Bs[2][8192];
  const int t = threadIdx.x;
  const int lane = t & 63;
  const int w = t >> 6;
  const int wr = (w >> 1) * 64, wc = (w & 1) * 64;
  const int fr = lane & 15;
  const int kg = lane >> 4;

  const int srow = lane >> 3;                 // 0..7 within 8-row chunk
  const int su = ((lane & 7) ^ srow) * 8;     // pre-swizzled global u16-col
  const u16* gA[4];
  const u16* gB[4];
  int ldsOff[4];
#pragma unroll
  for (int i = 0; i < 4; ++i) {
    const int c = w + i * 4;                  // chunk 0..15, 8 rows each
    gA[i] = A + (size_t)(tm + c * 8 + srow) * K + su;
    gB[i] = B + (size_t)(tn + c * 8 + srow) * K + su;
    ldsOff[i] = c * 512;                      // u16 offset of chunk
  }

  f32x4 acc[4][4];
#pragma unroll
  for (int m = 0; m < 4; ++m)
#pragma unroll
    for (int n = 0; n < 4; ++n) acc[m][n] = (f32x4){0.f, 0.f, 0.f, 0.f};

  const int nk = K >> 6;   // BK=64
  // prologue: stage tile 0 into buf 0
#pragma unroll
  for (int i = 0; i < 4; ++i) {
    gld16(gA[i], &As[0][ldsOff[i]]);
    gld16(gB[i], &Bs[0][ldsOff[i]]);
  }
  __syncthreads();   // drains vmcnt

  for (int kt = 0; kt < nk; ++kt) {
    const int cb = kt & 1;
    if (kt + 1 < nk) {   // issue next-tile loads FIRST (latency hides under compute)
      const int ko = (kt + 1) << 6;
#pragma unroll
      for (int i = 0; i < 4; ++i) {
        gld16(gA[i] + ko, &As[cb ^ 1][ldsOff[i]]);
        gld16(gB[i] + ko, &Bs[cb ^ 1][ldsOff[i]]);
      }
    }
    __builtin_amdgcn_sched_barrier(0);   // pin: stage-issue stays above compute
#pragma unroll
    for (int ks = 0; ks < 2; ++ks) {
      const int un = ((ks * 4 + kg) ^ (fr & 7)) << 4;   // byte offset of swizzled 16B unit
      bf16x8 af[4], bff[4];
#pragma unroll
      for (int m = 0; m < 4; ++m)
        af[m] = *(const bf16x8*)((const char*)As[cb] + (wr + m * 16 + fr) * 128 + un);
#pragma unroll
      for (int n = 0; n < 4; ++n)
        bff[n] = *(const bf16x8*)((const char*)Bs[cb] + (wc + n * 16 + fr) * 128 + un);
#pragma unroll
      for (int m = 0; m < 4; ++m)
#pragma unroll
        for (int n = 0; n < 4; ++n)
          acc[m][n] = __builtin_amdgcn_mfma_f32_16x16x32_bf16(af[m], bff[n], acc[m][n], 0, 0, 0);
    }
    __syncthreads();   // waits this iter's prefetch (vmcnt) + guards buffer swap
  }

  // epilogue: C/D layout col=lane&15, row=(lane>>4)*4+j  [m89/m91]
#pragma unroll
  for (int n = 0; n < 4; ++n) {
    int col = tn + wc + n * 16 + fr;
    float bv = (col < realN) ? bias[col] : 0.f;
#pragma unroll
    for (int m = 0; m < 4; ++m) {
#pragma unroll
      for (int j = 0; j < 4; ++j) {
        int row = tm + wr + m * 16 + kg * 4 + j;
        float v = acc[m][n][j] + bv;
        v = v > 0.f ? v : 0.01f * v;
        C[(size_t)row * ldc + col] = f2b(v);
      }
    }
  }
}

// ---------------- fused tail: barrier-free GEMM sections, 512 blocks ----------------
__global__ __launch_bounds__(256) void tail_kernel(
    const u16* __restrict__ hfc1, const u16* __restrict__ W2bf, const float* __restrict__ b2,
    const float* __restrict__ ldg, const float* __restrict__ lde,
    const u16* __restrict__ Wgbf, const float* __restrict__ bg,
    const u16* __restrict__ Webf, const float* __restrict__ be,
    float* __restrict__ out0, float* __restrict__ out1) {
  __shared__ float H16[N2P][16];     // [col][row] hfc2 tile
  __shared__ float dpart[2][4][16];  // [sec][wave][row] partial dots
  __shared__ float wt[2][16];        // softmax weights

  const int tm = blockIdx.x * 16;
  const int t = threadIdx.x;
  const int lane = t & 63;
  const int w = t >> 6;
  const int fr = lane & 15;
  const int kg = lane >> 4;
  const int n0 = w * 2;              // this wave's two 16-col n-tiles

  // ---- FC2: hfc2 = lrelu(hfc1 @ W2^T + b2), K=1024, barrier-free ----
  {
    f32x4 a0 = (f32x4){0.f, 0.f, 0.f, 0.f}, a1 = a0;
    const u16* Ap = hfc1 + (size_t)(tm + fr) * N1P + kg * 8;
    const u16* B0 = W2bf + (size_t)(n0 * 16 + fr) * N1P + kg * 8;
    const u16* B1 = B0 + (size_t)16 * N1P;
#pragma unroll 8
    for (int kt = 0; kt < N1P / 32; ++kt) {
      bf16x8 af = *(const bf16x8*)(Ap + kt * 32);
      bf16x8 f0 = *(const bf16x8*)(B0 + kt * 32);
      bf16x8 f1 = *(const bf16x8*)(B1 + kt * 32);
      a0 = __builtin_amdgcn_mfma_f32_16x16x32_bf16(af, f0, a0, 0, 0, 0);
      a1 = __builtin_amdgcn_mfma_f32_16x16x32_bf16(af, f1, a1, 0, 0, 0);
    }
#pragma unroll
    for (int n = 0; n < 2; ++n) {
      int col = (n0 + n) * 16 + fr;
      float bv = (col < N2R) ? b2[col] : 0.f;
      f32x4 v = n == 0 ? a0 : a1;
      f32x4 o;
#pragma unroll
      for (int j = 0; j < 4; ++j) {
        float x = v[j] + bv;
        o[j] = x > 0.f ? x : 0.01f * x;
      }
      *(f32x4*)&H16[col][kg * 4] = o;
    }
  }
  __syncthreads();

  // ---- G/E gate sections: tanh(ld @ W^T + b), dot with H16 ----
#pragma unroll 1
  for (int sec = 0; sec < 2; ++sec) {
    const float* ld = sec == 0 ? ldg : lde;
    const u16* Wb = sec == 0 ? Wgbf : Webf;
    const float* bb = sec == 0 ? bg : be;

    f32x4 a0 = (f32x4){0.f, 0.f, 0.f, 0.f}, a1 = a0;
    const float* Ap = ld + (size_t)(tm + fr) * DG + kg * 8;
    const u16* B0 = Wb + (size_t)(n0 * 16 + fr) * DG + kg * 8;
    const u16* B1 = B0 + (size_t)16 * DG;
#pragma unroll 4
    for (int kt = 0; kt < DG / 32; ++kt) {
      float4 v0 = *(const float4*)(Ap + kt * 32);
      float4 v1 = *(const float4*)(Ap + kt * 32 + 4);
      bf16x8 af;
      af[0] = (short)f2b(v0.x); af[1] = (short)f2b(v0.y);
      af[2] = (short)f2b(v0.z); af[3] = (short)f2b(v0.w);
      af[4] = (short)f2b(v1.x); af[5] = (short)f2b(v1.y);
      af[6] = (short)f2b(v1.z); af[7] = (short)f2b(v1.w);
      bf16x8 f0 = *(const bf16x8*)(B0 + kt * 32);
      bf16x8 f1 = *(const bf16x8*)(B1 + kt * 32);
      a0 = __builtin_amdgcn_mfma_f32_16x16x32_bf16(af, f0, a0, 0, 0, 0);
      a1 = __builtin_amdgcn_mfma_f32_16x16x32_bf16(af, f1, a1, 0, 0, 0);
    }
    float dv[4] = {0.f, 0.f, 0.f, 0.f};
#pragma unroll
    for (int n = 0; n < 2; ++n) {
      int col = (n0 + n) * 16 + fr;
      float bv = (col < N2R) ? bb[col] : 0.f;
      f32x4 v = n == 0 ? a0 : a1;
      f32x4 h = *(const f32x4*)&H16[col][kg * 4];
#pragma unroll
      for (int j = 0; j < 4; ++j)
        dv[j] += tanh_fast(v[j] + bv) * h[j];
    }
#pragma unroll
    for (int j = 0; j < 4; ++j) {
      float v = dv[j];
      v += __shfl_xor(v, 1);
      v += __shfl_xor(v, 2);
      v += __shfl_xor(v, 4);
      v += __shfl_xor(v, 8);
      dv[j] = v;
    }
    if (fr == 0) {
#pragma unroll
      for (int j = 0; j < 4; ++j) dpart[sec][w][kg * 4 + j] = dv[j];
    }
  }
  __syncthreads();

  // ---- softmax per row ----
  if (t < 16) {
    float ag = dpart[0][0][t] + dpart[0][1][t] + dpart[0][2][t] + dpart[0][3][t];
    float ae = dpart[1][0][t] + dpart[1][1][t] + dpart[1][2][t] + dpart[1][3][t];
    float mm = fmaxf(ag, ae);
    float eg = __expf(ag - mm), eo = __expf(ae - mm);
    float inv = 1.f / (eg + eo);
    wt[0][t] = eg * inv;
    wt[1][t] = eo * inv;
  }
  __syncthreads();

  // ---- scale + write both outputs (coalesced float4) ----
  for (int i = t; i < 16 * (DG / 4); i += 256) {
    int r = i >> 7, c = i & 127;
    float w0 = wt[0][r], w1 = wt[1][r];
    size_t off = (size_t)(tm + r) * DG + c * 4;
    float4 a = *(const float4*)(ldg + off);
    a.x *= w0; a.y *= w0; a.z *= w0; a.w *= w0;
    *(float4*)(out0 + off) = a;
    float4 b = *(const float4*)(lde + off);
    b.x *= w1; b.y *= w1; b.z *= w1; b.w *= w1;
    *(float4*)(out1 + off) = b;
  }
}

extern "C" void kernel_launch(void* const* d_in, const int* in_sizes, int n_in,
                              void* d_out, int out_size, void* d_ws, size_t ws_size,
                              hipStream_t stream) {
  const float* ld_gcn = (const float*)d_in[0];
  const float* ld_enc = (const float*)d_in[1];
  const int*   xi     = (const int*)d_in[2];
  const int*   yi     = (const int*)d_in[3];
  const float* H_emb  = (const float*)d_in[4];
  const float* conv_w = (const float*)d_in[5];
  const float* conv_b = (const float*)d_in[6];
  const float* W1     = (const float*)d_in[7];
  const float* b1     = (const float*)d_in[8];
  const float* W2     = (const float*)d_in[9];
  const float* b2     = (const float*)d_in[10];
  const float* Wg     = (const float*)d_in[11];
  const float* bg     = (const float*)d_in[12];
  const float* We     = (const float*)d_in[13];
  const float* be     = (const float*)d_in[14];

  char* ws = (char*)d_ws;
  size_t off = 0;
  auto alloc = [&](size_t bytes) -> void* {
    void* p = ws + off;
    off = (off + bytes + 255) & ~(size_t)255;
    return p;
  };
  u16* Abuf = (u16*)alloc(240ull * FDIM * 2);
  u16* Bbuf = (u16*)alloc(404ull * FDIM * 2);
  u16* cbf  = (u16*)alloc((size_t)NROWS * FDIM * 2);
  u16* W1bf = (u16*)alloc((size_t)N1P * FDIM * 2);
  u16* W2bf = (u16*)alloc((size_t)N2P * N1P * 2);
  u16* Wgbf = (u16*)alloc((size_t)N2P * DG * 2);
  u16* Webf = (u16*)alloc((size_t)N2P * DG * 2);
  u16* hfc1 = (u16*)alloc((size_t)NROWS * N1P * 2);
  if (ws_size < off) return;  // ~96 MB needed

  prep_kernel<<<2756, 256, 0, stream>>>(W1, W2, Wg, We, H_emb, conv_w, conv_b,
                                        W1bf, W2bf, Wgbf, Webf, Abuf, Bbuf);
  conv_combine_kernel<<<NROWS, 256, 0, stream>>>(Abuf, Bbuf, xi, yi, cbf);

  fc1_kernel<<<dim3((NROWS / 128) * (N1P / 128)), 256, 0, stream>>>(
      cbf, W1bf, b1, N1R, hfc1, FDIM, N1P, N1P / 128);

  float* out0 = (float*)d_out;
  float* out1 = out0 + (size_t)NROWS * DG;
  tail_kernel<<<NROWS / 16, 256, 0, stream>>>(
      hfc1, W2bf, b2, ld_gcn, ld_enc, Wgbf, bg, Webf, be, out0, out1);
}